// Round 2
// baseline (743.981 us; speedup 1.0000x reference)
//
#include <hip/hip_runtime.h>
#include <cstdint>
#include <cstddef>

// ---------------------------------------------------------------------------
// GAT 3-layer forward, MI355X.
// Pipeline per call:
//   1. deg histogram over dst (int atomics)
//   2. exclusive scan -> rowptr (3 small kernels)
//   3. scatter edges into CSR by dst (atomic cursor)
//   4. per layer: fused GEMM+alpha kernel, then wave-per-node aggregation
//      (self-loop handled analytically; no float atomics anywhere)
// NOTE: harness delivers integer inputs as int32 — edge_index is const int*.
// ---------------------------------------------------------------------------

__device__ __forceinline__ float leaky(float v) { return v > 0.f ? v : 0.2f * v; }

// -------------------- CSR build --------------------

__global__ void count_kernel(const int* __restrict__ ei, int* __restrict__ deg, int E) {
    int e = blockIdx.x * 256 + threadIdx.x;
    if (e < E) atomicAdd(&deg[ei[E + e]], 1);
}

__global__ void scan1_kernel(const int* __restrict__ deg, int* __restrict__ part,
                             int* __restrict__ bsum, int N) {
    __shared__ int sh[256];
    int t = threadIdx.x;
    int i = blockIdx.x * 256 + t;
    int v = (i < N) ? deg[i] : 0;
    sh[t] = v;
    __syncthreads();
    for (int off = 1; off < 256; off <<= 1) {
        int a = (t >= off) ? sh[t - off] : 0;
        __syncthreads();
        sh[t] += a;
        __syncthreads();
    }
    if (i < N) part[i] = sh[t] - v;           // exclusive within block
    if (t == 255) bsum[blockIdx.x] = sh[255]; // block total
}

__global__ void scan2_kernel(const int* __restrict__ bsum, int* __restrict__ boff, int nb) {
    __shared__ int sh[256];
    int t = threadIdx.x;
    int v = (t < nb) ? bsum[t] : 0;
    sh[t] = v;
    __syncthreads();
    for (int off = 1; off < 256; off <<= 1) {
        int a = (t >= off) ? sh[t - off] : 0;
        __syncthreads();
        sh[t] += a;
        __syncthreads();
    }
    if (t < nb) boff[t] = sh[t] - v;          // exclusive block offsets
}

__global__ void scan3_kernel(int* __restrict__ rowptr, const int* __restrict__ boff,
                             int* __restrict__ cursor, int N, int E) {
    int i = blockIdx.x * 256 + threadIdx.x;
    if (i < N) {
        int r = rowptr[i] + boff[blockIdx.x];
        rowptr[i] = r;
        cursor[i] = r;
    }
    if (i == 0) rowptr[N] = E;
}

__global__ void scatter_kernel(const int* __restrict__ ei, int* __restrict__ cursor,
                               int* __restrict__ csr, int E) {
    int e = blockIdx.x * 256 + threadIdx.x;
    if (e < E) {
        int s = ei[e];
        int d = ei[E + e];
        int p = atomicAdd(&cursor[d], 1);
        csr[p] = s;
    }
}

// -------------------- fused GEMM + alpha --------------------
// Block: 256 threads = 64 nodes x 16 fout-groups. Thread: 4 nodes x FT fouts.
// W^T staged in LDS (pitch FIN+4 -> <=2-way bank conflicts, free on CDNA4).
// Epilogue: alpha_src/alpha_dst via 16-lane shuffle reduction (lanes sharing
// a node are 16 consecutive lanes of the same wave).

template <int FIN, int FOUT, int FT>
__global__ __launch_bounds__(256) void gemm_alpha_kernel(
    const float* __restrict__ X, const float* __restrict__ W,
    const float* __restrict__ avs, const float* __restrict__ avd,
    float* __restrict__ H, float* __restrict__ asrc, float* __restrict__ adst, int N) {
    constexpr int PITCH = FIN + 4;
    __shared__ float Wt[16 * FT][PITCH];
    for (int idx = threadIdx.x; idx < 16 * FT * FIN; idx += 256) {
        int k = idx % FIN, f = idx / FIN;
        Wt[f][k] = (f < FOUT) ? W[k * FOUT + f] : 0.f;
    }
    __syncthreads();

    const int j = threadIdx.x & 15;   // fout group
    const int i = threadIdx.x >> 4;   // node group (0..15)
    const int nbase = blockIdx.x * 64 + i * 4;

    float acc[4][FT];
#pragma unroll
    for (int m = 0; m < 4; m++)
#pragma unroll
        for (int c = 0; c < FT; c++) acc[m][c] = 0.f;

    const float* xrow[4];
#pragma unroll
    for (int m = 0; m < 4; m++) {
        int n = nbase + m;
        if (n > N - 1) n = N - 1;  // clamp loads; stores guarded below
        xrow[m] = X + (size_t)n * FIN;
    }

    for (int k = 0; k < FIN; k += 4) {
        float4 xv[4];
#pragma unroll
        for (int m = 0; m < 4; m++) xv[m] = *(const float4*)(xrow[m] + k);
#pragma unroll
        for (int c = 0; c < FT; c++) {
            float4 wv = *(const float4*)&Wt[j * FT + c][k];
#pragma unroll
            for (int m = 0; m < 4; m++) {
                acc[m][c] = fmaf(xv[m].x, wv.x,
                             fmaf(xv[m].y, wv.y,
                              fmaf(xv[m].z, wv.z,
                               fmaf(xv[m].w, wv.w, acc[m][c]))));
            }
        }
    }

    float asv[FT], adv[FT];
#pragma unroll
    for (int c = 0; c < FT; c++) {
        int f = j * FT + c;
        asv[c] = (f < FOUT) ? avs[f] : 0.f;
        adv[c] = (f < FOUT) ? avd[f] : 0.f;
    }

#pragma unroll
    for (int m = 0; m < 4; m++) {
        int n = nbase + m;
        float ps = 0.f, pd = 0.f;
#pragma unroll
        for (int c = 0; c < FT; c++) {
            ps = fmaf(acc[m][c], asv[c], ps);
            pd = fmaf(acc[m][c], adv[c], pd);
        }
#pragma unroll
        for (int off = 1; off < 16; off <<= 1) {
            ps += __shfl_xor(ps, off, 64);
            pd += __shfl_xor(pd, off, 64);
        }
        if (n < N) {
            if (j == 0) { asrc[n] = ps; adst[n] = pd; }
#pragma unroll
            for (int c = 0; c < FT; c++) {
                int f = j * FT + c;
                if (f < FOUT) H[(size_t)n * FOUT + f] = acc[m][c];
            }
        }
    }
}

// -------------------- aggregation (segment softmax + weighted sum) --------------------
// One wave per destination node; lane = feature. Self-loop added analytically.

template <int FOUT, bool RELU>
__global__ __launch_bounds__(256) void agg_kernel(
    const int* __restrict__ rowptr, const int* __restrict__ csr,
    const float* __restrict__ asrc, const float* __restrict__ adst,
    const float* __restrict__ H, const float* __restrict__ bias,
    float* __restrict__ OUT, int N) {
    int n = blockIdx.x * 4 + (threadIdx.x >> 6);
    if (n >= N) return;
    int lane = threadIdx.x & 63;
    int rs = rowptr[n], re = rowptr[n + 1];
    float ad_n = adst[n];
    float lself = leaky(asrc[n] + ad_n);

    // phase 1: segment max (lane-strided over edges)
    float m = lself;
    for (int e = rs + lane; e < re; e += 64)
        m = fmaxf(m, leaky(asrc[csr[e]] + ad_n));
#pragma unroll
    for (int off = 32; off; off >>= 1) m = fmaxf(m, __shfl_xor(m, off, 64));

    float eself = __expf(lself - m);

    if constexpr (FOUT == 1) {
        float ssum = 0.f, accv = 0.f;
        for (int e = rs + lane; e < re; e += 64) {
            int s = csr[e];
            float w = __expf(leaky(asrc[s] + ad_n) - m);
            ssum += w;
            accv = fmaf(w, H[s], accv);
        }
#pragma unroll
        for (int off = 32; off; off >>= 1) {
            ssum += __shfl_xor(ssum, off, 64);
            accv += __shfl_xor(accv, off, 64);
        }
        ssum += eself;
        accv = fmaf(eself, H[n], accv);
        if (lane == 0) {
            float o = accv / (ssum + 1e-16f) + bias[0];
            if (RELU) o = fmaxf(o, 0.f);
            OUT[n] = o;
        }
    } else {
        int f = lane;
        float hvn = (f < FOUT) ? H[(size_t)n * FOUT + f] : 0.f;
        float ssum = eself;
        float accv = eself * hvn;
        for (int e = rs; e < re; e++) {
            int s = csr[e];                              // broadcast load
            float w = __expf(leaky(asrc[s] + ad_n) - m); // redundant per lane (cheap)
            ssum += w;
            float hs = (f < FOUT) ? H[(size_t)s * FOUT + f] : 0.f;
            accv = fmaf(w, hs, accv);
        }
        if (f < FOUT) {
            float o = accv / (ssum + 1e-16f) + bias[f];
            if (RELU) o = fmaxf(o, 0.f);
            OUT[(size_t)n * FOUT + f] = o;
        }
    }
}

// -------------------- host launcher --------------------

extern "C" void kernel_launch(void* const* d_in, const int* in_sizes, int n_in,
                              void* d_out, int out_size, void* d_ws, size_t ws_size,
                              hipStream_t stream) {
    const float* x      = (const float*)d_in[0];
    const int*   ei     = (const int*)d_in[1];   // int32 per harness convention
    // d_in[2] = edge_attr: ignored by reference (no edge_dim)
    const float* W1  = (const float*)d_in[3];
    const float* as1 = (const float*)d_in[4];
    const float* ad1 = (const float*)d_in[5];
    const float* b1  = (const float*)d_in[6];
    const float* W2  = (const float*)d_in[7];
    const float* as2 = (const float*)d_in[8];
    const float* ad2 = (const float*)d_in[9];
    const float* b2  = (const float*)d_in[10];
    const float* W3  = (const float*)d_in[11];
    const float* as3 = (const float*)d_in[12];
    const float* ad3 = (const float*)d_in[13];
    const float* b3  = (const float*)d_in[14];

    const int N = in_sizes[0] / 256;   // 50000
    const int E = in_sizes[1] / 2;     // 1600000

    // workspace carve (256B-aligned bump allocator). Buffers aliased across
    // layers to keep total ~30 MB: h (N*60) reused for h1/h2/h3, act (N*60)
    // reused for act1/act2.
    char* p = (char*)d_ws;
    auto alloc = [&](size_t bytes) -> void* {
        void* r = (void*)p;
        p += ((bytes + 255) / 256) * 256;
        return r;
    };
    int*   deg    = (int*)alloc((size_t)N * 4);
    int*   rowptr = (int*)alloc(((size_t)N + 1) * 4);
    int*   cursor = (int*)alloc((size_t)N * 4);
    int*   bsum   = (int*)alloc(1024);
    int*   boff   = (int*)alloc(1024);
    int*   csr    = (int*)alloc((size_t)E * 4);
    float* hbuf   = (float*)alloc((size_t)N * 60 * 4);  // h1(48)/h2(60)/h3(1)
    float* actbuf = (float*)alloc((size_t)N * 60 * 4);  // act1(48)/act2(60)
    float* asrc   = (float*)alloc((size_t)N * 4);
    float* adst   = (float*)alloc((size_t)N * 4);

    // ---- CSR build (reused by all 3 layers) ----
    hipMemsetAsync(deg, 0, (size_t)N * 4, stream);
    int ebl = (E + 255) / 256;
    count_kernel<<<ebl, 256, 0, stream>>>(ei, deg, E);
    int nb = (N + 255) / 256;
    scan1_kernel<<<nb, 256, 0, stream>>>(deg, rowptr, bsum, N);
    scan2_kernel<<<1, 256, 0, stream>>>(bsum, boff, nb);
    scan3_kernel<<<nb, 256, 0, stream>>>(rowptr, boff, cursor, N, E);
    scatter_kernel<<<ebl, 256, 0, stream>>>(ei, cursor, csr, E);

    int gblocks = (N + 63) / 64;
    int ablocks = (N + 3) / 4;

    // ---- layer 1: 256 -> 48, relu ----
    gemm_alpha_kernel<256, 48, 3><<<gblocks, 256, 0, stream>>>(x, W1, as1, ad1, hbuf, asrc, adst, N);
    agg_kernel<48, true><<<ablocks, 256, 0, stream>>>(rowptr, csr, asrc, adst, hbuf, b1, actbuf, N);

    // ---- layer 2: 48 -> 60, relu ----
    gemm_alpha_kernel<48, 60, 4><<<gblocks, 256, 0, stream>>>(actbuf, W2, as2, ad2, hbuf, asrc, adst, N);
    agg_kernel<60, true><<<ablocks, 256, 0, stream>>>(rowptr, csr, asrc, adst, hbuf, b2, actbuf, N);

    // ---- layer 3: 60 -> 1, no relu, straight to d_out ----
    gemm_alpha_kernel<60, 1, 1><<<gblocks, 256, 0, stream>>>(actbuf, W3, as3, ad3, hbuf, asrc, adst, N);
    agg_kernel<1, false><<<ablocks, 256, 0, stream>>>(rowptr, csr, asrc, adst, hbuf, b3, (float*)d_out, N);
}

// Round 3
// 542.104 us; speedup vs baseline: 1.3724x; 1.3724x over previous
//
#include <hip/hip_runtime.h>
#include <cstdint>
#include <cstddef>

// ---------------------------------------------------------------------------
// GAT 3-layer forward, MI355X.
// Round 3: agg kernels lose the segment-max pass (fp32 exp can't overflow:
// |logits| <~ 20) and gain an 8-deep edge unroll for memory-level parallelism
// (round-2 profile: aggs latency-bound at 1.25 TB/s, VALUBusy 30%, VGPR 16).
// ---------------------------------------------------------------------------

__device__ __forceinline__ float leaky(float v) { return v > 0.f ? v : 0.2f * v; }

// -------------------- CSR build --------------------

__global__ void count_kernel(const int* __restrict__ ei, int* __restrict__ deg, int E) {
    int e = blockIdx.x * 256 + threadIdx.x;
    if (e < E) atomicAdd(&deg[ei[E + e]], 1);
}

__global__ void scan1_kernel(const int* __restrict__ deg, int* __restrict__ part,
                             int* __restrict__ bsum, int N) {
    __shared__ int sh[256];
    int t = threadIdx.x;
    int i = blockIdx.x * 256 + t;
    int v = (i < N) ? deg[i] : 0;
    sh[t] = v;
    __syncthreads();
    for (int off = 1; off < 256; off <<= 1) {
        int a = (t >= off) ? sh[t - off] : 0;
        __syncthreads();
        sh[t] += a;
        __syncthreads();
    }
    if (i < N) part[i] = sh[t] - v;           // exclusive within block
    if (t == 255) bsum[blockIdx.x] = sh[255]; // block total
}

__global__ void scan2_kernel(const int* __restrict__ bsum, int* __restrict__ boff, int nb) {
    __shared__ int sh[256];
    int t = threadIdx.x;
    int v = (t < nb) ? bsum[t] : 0;
    sh[t] = v;
    __syncthreads();
    for (int off = 1; off < 256; off <<= 1) {
        int a = (t >= off) ? sh[t - off] : 0;
        __syncthreads();
        sh[t] += a;
        __syncthreads();
    }
    if (t < nb) boff[t] = sh[t] - v;          // exclusive block offsets
}

__global__ void scan3_kernel(int* __restrict__ rowptr, const int* __restrict__ boff,
                             int* __restrict__ cursor, int N, int E) {
    int i = blockIdx.x * 256 + threadIdx.x;
    if (i < N) {
        int r = rowptr[i] + boff[blockIdx.x];
        rowptr[i] = r;
        cursor[i] = r;
    }
    if (i == 0) rowptr[N] = E;
}

__global__ void scatter_kernel(const int* __restrict__ ei, int* __restrict__ cursor,
                               int* __restrict__ csr, int E) {
    int e = blockIdx.x * 256 + threadIdx.x;
    if (e < E) {
        int s = ei[e];
        int d = ei[E + e];
        int p = atomicAdd(&cursor[d], 1);
        csr[p] = s;
    }
}

// -------------------- fused GEMM + alpha --------------------

template <int FIN, int FOUT, int FT>
__global__ __launch_bounds__(256) void gemm_alpha_kernel(
    const float* __restrict__ X, const float* __restrict__ W,
    const float* __restrict__ avs, const float* __restrict__ avd,
    float* __restrict__ H, float* __restrict__ asrc, float* __restrict__ adst, int N) {
    constexpr int PITCH = FIN + 4;
    __shared__ float Wt[16 * FT][PITCH];
    for (int idx = threadIdx.x; idx < 16 * FT * FIN; idx += 256) {
        int k = idx % FIN, f = idx / FIN;
        Wt[f][k] = (f < FOUT) ? W[k * FOUT + f] : 0.f;
    }
    __syncthreads();

    const int j = threadIdx.x & 15;   // fout group
    const int i = threadIdx.x >> 4;   // node group (0..15)
    const int nbase = blockIdx.x * 64 + i * 4;

    float acc[4][FT];
#pragma unroll
    for (int m = 0; m < 4; m++)
#pragma unroll
        for (int c = 0; c < FT; c++) acc[m][c] = 0.f;

    const float* xrow[4];
#pragma unroll
    for (int m = 0; m < 4; m++) {
        int n = nbase + m;
        if (n > N - 1) n = N - 1;  // clamp loads; stores guarded below
        xrow[m] = X + (size_t)n * FIN;
    }

    for (int k = 0; k < FIN; k += 4) {
        float4 xv[4];
#pragma unroll
        for (int m = 0; m < 4; m++) xv[m] = *(const float4*)(xrow[m] + k);
#pragma unroll
        for (int c = 0; c < FT; c++) {
            float4 wv = *(const float4*)&Wt[j * FT + c][k];
#pragma unroll
            for (int m = 0; m < 4; m++) {
                acc[m][c] = fmaf(xv[m].x, wv.x,
                             fmaf(xv[m].y, wv.y,
                              fmaf(xv[m].z, wv.z,
                               fmaf(xv[m].w, wv.w, acc[m][c]))));
            }
        }
    }

    float asv[FT], adv[FT];
#pragma unroll
    for (int c = 0; c < FT; c++) {
        int f = j * FT + c;
        asv[c] = (f < FOUT) ? avs[f] : 0.f;
        adv[c] = (f < FOUT) ? avd[f] : 0.f;
    }

#pragma unroll
    for (int m = 0; m < 4; m++) {
        int n = nbase + m;
        float ps = 0.f, pd = 0.f;
#pragma unroll
        for (int c = 0; c < FT; c++) {
            ps = fmaf(acc[m][c], asv[c], ps);
            pd = fmaf(acc[m][c], adv[c], pd);
        }
#pragma unroll
        for (int off = 1; off < 16; off <<= 1) {
            ps += __shfl_xor(ps, off, 64);
            pd += __shfl_xor(pd, off, 64);
        }
        if (n < N) {
            if (j == 0) { asrc[n] = ps; adst[n] = pd; }
#pragma unroll
            for (int c = 0; c < FT; c++) {
                int f = j * FT + c;
                if (f < FOUT) H[(size_t)n * FOUT + f] = acc[m][c];
            }
        }
    }
}

// -------------------- aggregation (segment softmax + weighted sum) --------------------
// One wave per destination node; lane = feature. Self-loop handled analytically.
// No max pass (exp can't overflow: |logit| <~ 20). Edge loop unrolled x8 for MLP.

template <int FOUT, bool RELU>
__global__ __launch_bounds__(256) void agg_kernel(
    const int* __restrict__ rowptr, const int* __restrict__ csr,
    const float* __restrict__ asrc, const float* __restrict__ adst,
    const float* __restrict__ H, const float* __restrict__ bias,
    float* __restrict__ OUT, int N) {
    int n = blockIdx.x * 4 + (threadIdx.x >> 6);
    if (n >= N) return;
    int lane = threadIdx.x & 63;
    int rs = rowptr[n], re = rowptr[n + 1];
    float ad_n = adst[n];
    float wself = __expf(leaky(asrc[n] + ad_n));

    if constexpr (FOUT == 1) {
        float ssum = 0.f, accv = 0.f;
        for (int e = rs + lane; e < re; e += 64) {
            int s = csr[e];
            float w = __expf(leaky(asrc[s] + ad_n));
            ssum += w;
            accv = fmaf(w, H[s], accv);
        }
#pragma unroll
        for (int off = 32; off; off >>= 1) {
            ssum += __shfl_xor(ssum, off, 64);
            accv += __shfl_xor(accv, off, 64);
        }
        ssum += wself;
        accv = fmaf(wself, H[n], accv);
        if (lane == 0) {
            float o = accv / (ssum + 1e-16f) + bias[0];
            if (RELU) o = fmaxf(o, 0.f);
            OUT[n] = o;
        }
    } else {
        const int f = lane;
        const int fc = (f < FOUT) ? f : FOUT - 1;  // clamp: lanes >= FOUT load dup, never store
        float hvn = H[(size_t)n * FOUT + fc];
        float ssum = wself;
        float acc = wself * hvn;
        int e = rs;
        for (; e + 8 <= re; e += 8) {
            int s[8];
            float a[8], h[8];
#pragma unroll
            for (int u = 0; u < 8; u++) s[u] = csr[e + u];          // broadcast loads
#pragma unroll
            for (int u = 0; u < 8; u++) a[u] = asrc[s[u]];          // 8 independent gathers
#pragma unroll
            for (int u = 0; u < 8; u++) h[u] = H[(size_t)s[u] * FOUT + fc];
#pragma unroll
            for (int u = 0; u < 8; u++) {
                float w = __expf(leaky(a[u] + ad_n));
                ssum += w;
                acc = fmaf(w, h[u], acc);
            }
        }
        for (; e < re; e++) {
            int s = csr[e];
            float w = __expf(leaky(asrc[s] + ad_n));
            float hv = H[(size_t)s * FOUT + fc];
            ssum += w;
            acc = fmaf(w, hv, acc);
        }
        if (f < FOUT) {
            float o = acc / (ssum + 1e-16f) + bias[f];
            if (RELU) o = fmaxf(o, 0.f);
            OUT[(size_t)n * FOUT + f] = o;
        }
    }
}

// -------------------- host launcher --------------------

extern "C" void kernel_launch(void* const* d_in, const int* in_sizes, int n_in,
                              void* d_out, int out_size, void* d_ws, size_t ws_size,
                              hipStream_t stream) {
    const float* x      = (const float*)d_in[0];
    const int*   ei     = (const int*)d_in[1];   // int32 per harness convention
    // d_in[2] = edge_attr: ignored by reference (no edge_dim)
    const float* W1  = (const float*)d_in[3];
    const float* as1 = (const float*)d_in[4];
    const float* ad1 = (const float*)d_in[5];
    const float* b1  = (const float*)d_in[6];
    const float* W2  = (const float*)d_in[7];
    const float* as2 = (const float*)d_in[8];
    const float* ad2 = (const float*)d_in[9];
    const float* b2  = (const float*)d_in[10];
    const float* W3  = (const float*)d_in[11];
    const float* as3 = (const float*)d_in[12];
    const float* ad3 = (const float*)d_in[13];
    const float* b3  = (const float*)d_in[14];

    const int N = in_sizes[0] / 256;   // 50000
    const int E = in_sizes[1] / 2;     // 1600000

    char* p = (char*)d_ws;
    auto alloc = [&](size_t bytes) -> void* {
        void* r = (void*)p;
        p += ((bytes + 255) / 256) * 256;
        return r;
    };
    int*   deg    = (int*)alloc((size_t)N * 4);
    int*   rowptr = (int*)alloc(((size_t)N + 1) * 4);
    int*   cursor = (int*)alloc((size_t)N * 4);
    int*   bsum   = (int*)alloc(1024);
    int*   boff   = (int*)alloc(1024);
    int*   csr    = (int*)alloc((size_t)E * 4);
    float* hbuf   = (float*)alloc((size_t)N * 60 * 4);  // h1(48)/h2(60)/h3(1)
    float* actbuf = (float*)alloc((size_t)N * 60 * 4);  // act1(48)/act2(60)
    float* asrc   = (float*)alloc((size_t)N * 4);
    float* adst   = (float*)alloc((size_t)N * 4);

    // ---- CSR build (reused by all 3 layers) ----
    hipMemsetAsync(deg, 0, (size_t)N * 4, stream);
    int ebl = (E + 255) / 256;
    count_kernel<<<ebl, 256, 0, stream>>>(ei, deg, E);
    int nb = (N + 255) / 256;
    scan1_kernel<<<nb, 256, 0, stream>>>(deg, rowptr, bsum, N);
    scan2_kernel<<<1, 256, 0, stream>>>(bsum, boff, nb);
    scan3_kernel<<<nb, 256, 0, stream>>>(rowptr, boff, cursor, N, E);
    scatter_kernel<<<ebl, 256, 0, stream>>>(ei, cursor, csr, E);

    int gblocks = (N + 63) / 64;
    int ablocks = (N + 3) / 4;

    // ---- layer 1: 256 -> 48, relu ----
    gemm_alpha_kernel<256, 48, 3><<<gblocks, 256, 0, stream>>>(x, W1, as1, ad1, hbuf, asrc, adst, N);
    agg_kernel<48, true><<<ablocks, 256, 0, stream>>>(rowptr, csr, asrc, adst, hbuf, b1, actbuf, N);

    // ---- layer 2: 48 -> 60, relu ----
    gemm_alpha_kernel<48, 60, 4><<<gblocks, 256, 0, stream>>>(actbuf, W2, as2, ad2, hbuf, asrc, adst, N);
    agg_kernel<60, true><<<ablocks, 256, 0, stream>>>(rowptr, csr, asrc, adst, hbuf, b2, actbuf, N);

    // ---- layer 3: 60 -> 1, no relu, straight to d_out ----
    gemm_alpha_kernel<60, 1, 1><<<gblocks, 256, 0, stream>>>(actbuf, W3, as3, ad3, hbuf, asrc, adst, N);
    agg_kernel<1, false><<<ablocks, 256, 0, stream>>>(rowptr, csr, asrc, adst, hbuf, b3, (float*)d_out, N);
}

// Round 5
// 376.030 us; speedup vs baseline: 1.9785x; 1.4417x over previous
//
#include <hip/hip_runtime.h>
#include <cstdint>
#include <cstddef>

// ---------------------------------------------------------------------------
// GAT 3-layer forward, MI355X.
// Round 4 (resubmit after GPU acquisition timeout): CSR build rewritten as
// two-level bucketed counting sort.
// Round-3 profile: scatter_kernel wrote 101 MB HBM (16x amplification from
// random 4B writes) at 137 us. New scheme: coarse bin into 391 fixed-capacity
// bucket regions with per-tile burst reservations (~84 B single-writer
// bursts), then per-bucket fine sort entirely in LDS with coalesced flush.
// ---------------------------------------------------------------------------

__device__ __forceinline__ float leaky(float v) { return v > 0.f ? v : 0.2f * v; }

#define BSHIFT 7                 // 128 nodes per bucket
#define BCAP   5120              // slots per bucket region (mean 4096, +16 sigma)
#define CTILE  8192              // edges per coarse block

// -------------------- coarse bin: edges -> bucket regions --------------------
// record = (dst & 127) << 16 | src   (src < 65536, N = 50000)

__global__ __launch_bounds__(256) void coarse_bin_kernel(
    const int* __restrict__ ei, unsigned int* __restrict__ staged,
    int* __restrict__ gcursor, int E, int K) {
    __shared__ int hist[512];
    __shared__ int rank[512];
    __shared__ int base[512];
    for (int b = threadIdx.x; b < K; b += 256) { hist[b] = 0; rank[b] = 0; }
    __syncthreads();

    int e0 = blockIdx.x * CTILE;
    int e1 = min(E, e0 + CTILE);

    // phase A: histogram
    for (int e = e0 + threadIdx.x; e < e1; e += 256) {
        int d = ei[E + e];
        atomicAdd(&hist[d >> BSHIFT], 1);
    }
    __syncthreads();

    // phase B: reserve burst per bucket
    for (int b = threadIdx.x; b < K; b += 256) {
        int c = hist[b];
        base[b] = c ? atomicAdd(&gcursor[b], c) : 0;
    }
    __syncthreads();

    // phase C: ranked scatter (bursts are single-writer, contiguous)
    for (int e = e0 + threadIdx.x; e < e1; e += 256) {
        int s = ei[e];
        int d = ei[E + e];
        int b = d >> BSHIFT;
        int r = atomicAdd(&rank[b], 1);
        staged[(size_t)b * BCAP + base[b] + r] =
            ((unsigned int)(d & ((1 << BSHIFT) - 1)) << 16) | (unsigned int)s;
    }
}

// -------------------- bucket base scan (1 block) --------------------

__global__ __launch_bounds__(512) void bucket_scan_kernel(
    const int* __restrict__ gcursor, int* __restrict__ bbase, int K) {
    __shared__ int sh[512];
    int t = threadIdx.x;
    int v = (t < K) ? gcursor[t] : 0;
    sh[t] = v;
    __syncthreads();
    for (int off = 1; off < 512; off <<= 1) {
        int a = (t >= off) ? sh[t - off] : 0;
        __syncthreads();
        sh[t] += a;
        __syncthreads();
    }
    if (t < K) bbase[t] = sh[t] - v;   // exclusive
}

// -------------------- fine pass: bucket -> rowptr + sorted csr --------------------

__global__ __launch_bounds__(256) void fine_sort_kernel(
    const unsigned int* __restrict__ staged, const int* __restrict__ gcursor,
    const int* __restrict__ bbase, int* __restrict__ rowptr, int* __restrict__ csr,
    int N, int E) {
    __shared__ int cnt[128];
    __shared__ int off[128];
    __shared__ int lcsr[BCAP];
    const int b = blockIdx.x;
    const int t = threadIdx.x;
    const int c = gcursor[b];
    const int gb = bbase[b];
    const unsigned int* rec = staged + (size_t)b * BCAP;

    if (t < 128) cnt[t] = 0;
    __syncthreads();

    // per-node histogram
    for (int i = t; i < c; i += 256) atomicAdd(&cnt[rec[i] >> 16], 1);
    __syncthreads();

    // inclusive scan over 128 entries
    if (t < 128) off[t] = cnt[t];
    __syncthreads();
    for (int s = 1; s < 128; s <<= 1) {
        int a = (t >= s && t < 128) ? off[t - s] : 0;
        __syncthreads();
        if (t < 128) off[t] += a;
        __syncthreads();
    }

    // rowptr + convert cnt[] into running cursors (exclusive offsets)
    if (t < 128) {
        int excl = off[t] - cnt[t];
        int n = (b << BSHIFT) + t;
        if (n <= N) rowptr[n] = gb + excl;
        cnt[t] = excl;
    }
    if (b == 0 && t == 0) rowptr[N] = E;   // safety (idempotent with above)
    __syncthreads();

    // ranked scatter into LDS csr
    for (int i = t; i < c; i += 256) {
        unsigned int r = rec[i];
        int p = atomicAdd(&cnt[r >> 16], 1);
        lcsr[p] = (int)(r & 0xFFFFu);
    }
    __syncthreads();

    // coalesced flush
    for (int i = t; i < c; i += 256) csr[gb + i] = lcsr[i];
}

// -------------------- fused GEMM + alpha --------------------

template <int FIN, int FOUT, int FT>
__global__ __launch_bounds__(256) void gemm_alpha_kernel(
    const float* __restrict__ X, const float* __restrict__ W,
    const float* __restrict__ avs, const float* __restrict__ avd,
    float* __restrict__ H, float* __restrict__ asrc, float* __restrict__ adst, int N) {
    constexpr int PITCH = FIN + 4;
    __shared__ float Wt[16 * FT][PITCH];
    for (int idx = threadIdx.x; idx < 16 * FT * FIN; idx += 256) {
        int k = idx % FIN, f = idx / FIN;
        Wt[f][k] = (f < FOUT) ? W[k * FOUT + f] : 0.f;
    }
    __syncthreads();

    const int j = threadIdx.x & 15;   // fout group
    const int i = threadIdx.x >> 4;   // node group (0..15)
    const int nbase = blockIdx.x * 64 + i * 4;

    float acc[4][FT];
#pragma unroll
    for (int m = 0; m < 4; m++)
#pragma unroll
        for (int c = 0; c < FT; c++) acc[m][c] = 0.f;

    const float* xrow[4];
#pragma unroll
    for (int m = 0; m < 4; m++) {
        int n = nbase + m;
        if (n > N - 1) n = N - 1;  // clamp loads; stores guarded below
        xrow[m] = X + (size_t)n * FIN;
    }

    for (int k = 0; k < FIN; k += 4) {
        float4 xv[4];
#pragma unroll
        for (int m = 0; m < 4; m++) xv[m] = *(const float4*)(xrow[m] + k);
#pragma unroll
        for (int c = 0; c < FT; c++) {
            float4 wv = *(const float4*)&Wt[j * FT + c][k];
#pragma unroll
            for (int m = 0; m < 4; m++) {
                acc[m][c] = fmaf(xv[m].x, wv.x,
                             fmaf(xv[m].y, wv.y,
                              fmaf(xv[m].z, wv.z,
                               fmaf(xv[m].w, wv.w, acc[m][c]))));
            }
        }
    }

    float asv[FT], adv[FT];
#pragma unroll
    for (int c = 0; c < FT; c++) {
        int f = j * FT + c;
        asv[c] = (f < FOUT) ? avs[f] : 0.f;
        adv[c] = (f < FOUT) ? avd[f] : 0.f;
    }

#pragma unroll
    for (int m = 0; m < 4; m++) {
        int n = nbase + m;
        float ps = 0.f, pd = 0.f;
#pragma unroll
        for (int c = 0; c < FT; c++) {
            ps = fmaf(acc[m][c], asv[c], ps);
            pd = fmaf(acc[m][c], adv[c], pd);
        }
#pragma unroll
        for (int off = 1; off < 16; off <<= 1) {
            ps += __shfl_xor(ps, off, 64);
            pd += __shfl_xor(pd, off, 64);
        }
        if (n < N) {
            if (j == 0) { asrc[n] = ps; adst[n] = pd; }
#pragma unroll
            for (int c = 0; c < FT; c++) {
                int f = j * FT + c;
                if (f < FOUT) H[(size_t)n * FOUT + f] = acc[m][c];
            }
        }
    }
}

// -------------------- aggregation (segment softmax + weighted sum) --------------------
// One wave per destination node; lane = feature. Self-loop handled analytically.
// No max pass (exp can't overflow: |logit| <~ 20). Edge loop unrolled x8 for MLP.

template <int FOUT, bool RELU>
__global__ __launch_bounds__(256) void agg_kernel(
    const int* __restrict__ rowptr, const int* __restrict__ csr,
    const float* __restrict__ asrc, const float* __restrict__ adst,
    const float* __restrict__ H, const float* __restrict__ bias,
    float* __restrict__ OUT, int N) {
    int n = blockIdx.x * 4 + (threadIdx.x >> 6);
    if (n >= N) return;
    int lane = threadIdx.x & 63;
    int rs = rowptr[n], re = rowptr[n + 1];
    float ad_n = adst[n];
    float wself = __expf(leaky(asrc[n] + ad_n));

    if constexpr (FOUT == 1) {
        float ssum = 0.f, accv = 0.f;
        for (int e = rs + lane; e < re; e += 64) {
            int s = csr[e];
            float w = __expf(leaky(asrc[s] + ad_n));
            ssum += w;
            accv = fmaf(w, H[s], accv);
        }
#pragma unroll
        for (int off = 32; off; off >>= 1) {
            ssum += __shfl_xor(ssum, off, 64);
            accv += __shfl_xor(accv, off, 64);
        }
        ssum += wself;
        accv = fmaf(wself, H[n], accv);
        if (lane == 0) {
            float o = accv / (ssum + 1e-16f) + bias[0];
            if (RELU) o = fmaxf(o, 0.f);
            OUT[n] = o;
        }
    } else {
        const int f = lane;
        const int fc = (f < FOUT) ? f : FOUT - 1;  // clamp: lanes >= FOUT load dup, never store
        float hvn = H[(size_t)n * FOUT + fc];
        float ssum = wself;
        float acc = wself * hvn;
        int e = rs;
        for (; e + 8 <= re; e += 8) {
            int s[8];
            float a[8], h[8];
#pragma unroll
            for (int u = 0; u < 8; u++) s[u] = csr[e + u];          // broadcast loads
#pragma unroll
            for (int u = 0; u < 8; u++) a[u] = asrc[s[u]];          // 8 independent gathers
#pragma unroll
            for (int u = 0; u < 8; u++) h[u] = H[(size_t)s[u] * FOUT + fc];
#pragma unroll
            for (int u = 0; u < 8; u++) {
                float w = __expf(leaky(a[u] + ad_n));
                ssum += w;
                acc = fmaf(w, h[u], acc);
            }
        }
        for (; e < re; e++) {
            int s = csr[e];
            float w = __expf(leaky(asrc[s] + ad_n));
            float hv = H[(size_t)s * FOUT + fc];
            ssum += w;
            acc = fmaf(w, hv, acc);
        }
        if (f < FOUT) {
            float o = acc / (ssum + 1e-16f) + bias[f];
            if (RELU) o = fmaxf(o, 0.f);
            OUT[(size_t)n * FOUT + f] = o;
        }
    }
}

// -------------------- host launcher --------------------

extern "C" void kernel_launch(void* const* d_in, const int* in_sizes, int n_in,
                              void* d_out, int out_size, void* d_ws, size_t ws_size,
                              hipStream_t stream) {
    const float* x      = (const float*)d_in[0];
    const int*   ei     = (const int*)d_in[1];   // int32 per harness convention
    // d_in[2] = edge_attr: ignored by reference (no edge_dim)
    const float* W1  = (const float*)d_in[3];
    const float* as1 = (const float*)d_in[4];
    const float* ad1 = (const float*)d_in[5];
    const float* b1  = (const float*)d_in[6];
    const float* W2  = (const float*)d_in[7];
    const float* as2 = (const float*)d_in[8];
    const float* ad2 = (const float*)d_in[9];
    const float* b2  = (const float*)d_in[10];
    const float* W3  = (const float*)d_in[11];
    const float* as3 = (const float*)d_in[12];
    const float* ad3 = (const float*)d_in[13];
    const float* b3  = (const float*)d_in[14];

    const int N = in_sizes[0] / 256;   // 50000
    const int E = in_sizes[1] / 2;     // 1600000
    const int K = (N + (1 << BSHIFT) - 1) >> BSHIFT;   // 391 buckets

    char* p = (char*)d_ws;
    auto alloc = [&](size_t bytes) -> void* {
        void* r = (void*)p;
        p += ((bytes + 255) / 256) * 256;
        return r;
    };
    int*   gcursor = (int*)alloc(512 * 4);
    int*   bbase   = (int*)alloc(512 * 4);
    int*   rowptr  = (int*)alloc(((size_t)N + 1) * 4);
    int*   csr     = (int*)alloc((size_t)E * 4);
    float* hbuf    = (float*)alloc((size_t)N * 60 * 4);  // h1(48)/h2(60)/h3(1)
    float* actbuf  = (float*)alloc((size_t)N * 60 * 4);  // act1(48)/act2(60)
    float* asrc    = (float*)alloc((size_t)N * 4);
    float* adst    = (float*)alloc((size_t)N * 4);
    // staged bucket regions alias hbuf/actbuf (dead until layer-1 GEMM):
    unsigned int* staged = (unsigned int*)hbuf;          // K*BCAP*4 = 8 MB <= 24 MB

    // ---- CSR build (two-level bucketed counting sort) ----
    hipMemsetAsync(gcursor, 0, 512 * 4, stream);
    int cblocks = (E + CTILE - 1) / CTILE;
    coarse_bin_kernel<<<cblocks, 256, 0, stream>>>(ei, staged, gcursor, E, K);
    bucket_scan_kernel<<<1, 512, 0, stream>>>(gcursor, bbase, K);
    fine_sort_kernel<<<K, 256, 0, stream>>>(staged, gcursor, bbase, rowptr, csr, N, E);

    int gblocks = (N + 63) / 64;
    int ablocks = (N + 3) / 4;

    // ---- layer 1: 256 -> 48, relu ----
    gemm_alpha_kernel<256, 48, 3><<<gblocks, 256, 0, stream>>>(x, W1, as1, ad1, hbuf, asrc, adst, N);
    agg_kernel<48, true><<<ablocks, 256, 0, stream>>>(rowptr, csr, asrc, adst, hbuf, b1, actbuf, N);

    // ---- layer 2: 48 -> 60, relu ----
    gemm_alpha_kernel<48, 60, 4><<<gblocks, 256, 0, stream>>>(actbuf, W2, as2, ad2, hbuf, asrc, adst, N);
    agg_kernel<60, true><<<ablocks, 256, 0, stream>>>(rowptr, csr, asrc, adst, hbuf, b2, actbuf, N);

    // ---- layer 3: 60 -> 1, no relu, straight to d_out ----
    gemm_alpha_kernel<60, 1, 1><<<gblocks, 256, 0, stream>>>(actbuf, W3, as3, ad3, hbuf, asrc, adst, N);
    agg_kernel<1, false><<<ablocks, 256, 0, stream>>>(rowptr, csr, asrc, adst, hbuf, b3, (float*)d_out, N);
}

// Round 6
// 339.856 us; speedup vs baseline: 2.1891x; 1.1064x over previous
//
#include <hip/hip_runtime.h>
#include <cstdint>
#include <cstddef>

// ---------------------------------------------------------------------------
// GAT 3-layer forward, MI355X.
// Round 6: (a) H for layers 1-2 stored as bf16 padded to 128-B rows (64xbf16)
// -> each edge's row gather is exactly one cache line (was 2-2.5 fp32 lines);
// (b) agg computes each edge weight ONCE (phase A, one edge per lane, stashed
// in LDS) instead of 64x redundantly, then phase B sweeps LDS pairs with
// 8-deep unrolled bf16 row gathers. Round-5 profile: agg48/60 = 66 us each,
// FETCH 196 MB @ 3.2 TB/s, VALUBusy 58%.
// ---------------------------------------------------------------------------

__device__ __forceinline__ float leaky(float v) { return v > 0.f ? v : 0.2f * v; }

__device__ __forceinline__ unsigned short f2bf(float x) {
    unsigned int u = __float_as_uint(x);
    u = (u + 0x7FFFu + ((u >> 16) & 1u)) >> 16;   // RNE
    return (unsigned short)u;
}
__device__ __forceinline__ float bf2f(unsigned short b) {
    return __uint_as_float(((unsigned int)b) << 16);
}

#define BSHIFT 7                 // 128 nodes per bucket
#define BCAP   5120              // slots per bucket region (mean 4096, +16 sigma)
#define CTILE  8192              // edges per coarse block

// -------------------- coarse bin: edges -> bucket regions --------------------
// record = (dst & 127) << 16 | src   (src < 65536, N = 50000)

__global__ __launch_bounds__(256) void coarse_bin_kernel(
    const int* __restrict__ ei, unsigned int* __restrict__ staged,
    int* __restrict__ gcursor, int E, int K) {
    __shared__ int hist[512];
    __shared__ int rank[512];
    __shared__ int base[512];
    for (int b = threadIdx.x; b < K; b += 256) { hist[b] = 0; rank[b] = 0; }
    __syncthreads();

    int e0 = blockIdx.x * CTILE;
    int e1 = min(E, e0 + CTILE);

    for (int e = e0 + threadIdx.x; e < e1; e += 256) {
        int d = ei[E + e];
        atomicAdd(&hist[d >> BSHIFT], 1);
    }
    __syncthreads();

    for (int b = threadIdx.x; b < K; b += 256) {
        int c = hist[b];
        base[b] = c ? atomicAdd(&gcursor[b], c) : 0;
    }
    __syncthreads();

    for (int e = e0 + threadIdx.x; e < e1; e += 256) {
        int s = ei[e];
        int d = ei[E + e];
        int b = d >> BSHIFT;
        int r = atomicAdd(&rank[b], 1);
        staged[(size_t)b * BCAP + base[b] + r] =
            ((unsigned int)(d & ((1 << BSHIFT) - 1)) << 16) | (unsigned int)s;
    }
}

// -------------------- bucket base scan (1 block) --------------------

__global__ __launch_bounds__(512) void bucket_scan_kernel(
    const int* __restrict__ gcursor, int* __restrict__ bbase, int K) {
    __shared__ int sh[512];
    int t = threadIdx.x;
    int v = (t < K) ? gcursor[t] : 0;
    sh[t] = v;
    __syncthreads();
    for (int off = 1; off < 512; off <<= 1) {
        int a = (t >= off) ? sh[t - off] : 0;
        __syncthreads();
        sh[t] += a;
        __syncthreads();
    }
    if (t < K) bbase[t] = sh[t] - v;   // exclusive
}

// -------------------- fine pass: bucket -> rowptr + sorted csr --------------------

__global__ __launch_bounds__(256) void fine_sort_kernel(
    const unsigned int* __restrict__ staged, const int* __restrict__ gcursor,
    const int* __restrict__ bbase, int* __restrict__ rowptr, int* __restrict__ csr,
    int N, int E) {
    __shared__ int cnt[128];
    __shared__ int off[128];
    __shared__ int lcsr[BCAP];
    const int b = blockIdx.x;
    const int t = threadIdx.x;
    const int c = gcursor[b];
    const int gb = bbase[b];
    const unsigned int* rec = staged + (size_t)b * BCAP;

    if (t < 128) cnt[t] = 0;
    __syncthreads();

    for (int i = t; i < c; i += 256) atomicAdd(&cnt[rec[i] >> 16], 1);
    __syncthreads();

    if (t < 128) off[t] = cnt[t];
    __syncthreads();
    for (int s = 1; s < 128; s <<= 1) {
        int a = (t >= s && t < 128) ? off[t - s] : 0;
        __syncthreads();
        if (t < 128) off[t] += a;
        __syncthreads();
    }

    if (t < 128) {
        int excl = off[t] - cnt[t];
        int n = (b << BSHIFT) + t;
        if (n <= N) rowptr[n] = gb + excl;
        cnt[t] = excl;
    }
    if (b == 0 && t == 0) rowptr[N] = E;
    __syncthreads();

    for (int i = t; i < c; i += 256) {
        unsigned int r = rec[i];
        int p = atomicAdd(&cnt[r >> 16], 1);
        lcsr[p] = (int)(r & 0xFFFFu);
    }
    __syncthreads();

    for (int i = t; i < c; i += 256) csr[gb + i] = lcsr[i];
}

// -------------------- fused GEMM + alpha --------------------
// BF16OUT: store H as bf16 into padded 64-entry rows (layers 1-2); else fp32.

template <int FIN, int FOUT, int FT, bool BF16OUT>
__global__ __launch_bounds__(256) void gemm_alpha_kernel(
    const float* __restrict__ X, const float* __restrict__ W,
    const float* __restrict__ avs, const float* __restrict__ avd,
    void* __restrict__ Hout, float* __restrict__ asrc, float* __restrict__ adst, int N) {
    constexpr int PITCH = FIN + 4;
    __shared__ float Wt[16 * FT][PITCH];
    for (int idx = threadIdx.x; idx < 16 * FT * FIN; idx += 256) {
        int k = idx % FIN, f = idx / FIN;
        Wt[f][k] = (f < FOUT) ? W[k * FOUT + f] : 0.f;
    }
    __syncthreads();

    const int j = threadIdx.x & 15;   // fout group
    const int i = threadIdx.x >> 4;   // node group (0..15)
    const int nbase = blockIdx.x * 64 + i * 4;

    float acc[4][FT];
#pragma unroll
    for (int m = 0; m < 4; m++)
#pragma unroll
        for (int c = 0; c < FT; c++) acc[m][c] = 0.f;

    const float* xrow[4];
#pragma unroll
    for (int m = 0; m < 4; m++) {
        int n = nbase + m;
        if (n > N - 1) n = N - 1;  // clamp loads; stores guarded below
        xrow[m] = X + (size_t)n * FIN;
    }

    for (int k = 0; k < FIN; k += 4) {
        float4 xv[4];
#pragma unroll
        for (int m = 0; m < 4; m++) xv[m] = *(const float4*)(xrow[m] + k);
#pragma unroll
        for (int c = 0; c < FT; c++) {
            float4 wv = *(const float4*)&Wt[j * FT + c][k];
#pragma unroll
            for (int m = 0; m < 4; m++) {
                acc[m][c] = fmaf(xv[m].x, wv.x,
                             fmaf(xv[m].y, wv.y,
                              fmaf(xv[m].z, wv.z,
                               fmaf(xv[m].w, wv.w, acc[m][c]))));
            }
        }
    }

    float asv[FT], adv[FT];
#pragma unroll
    for (int c = 0; c < FT; c++) {
        int f = j * FT + c;
        asv[c] = (f < FOUT) ? avs[f] : 0.f;
        adv[c] = (f < FOUT) ? avd[f] : 0.f;
    }

#pragma unroll
    for (int m = 0; m < 4; m++) {
        int n = nbase + m;
        float ps = 0.f, pd = 0.f;
#pragma unroll
        for (int c = 0; c < FT; c++) {
            ps = fmaf(acc[m][c], asv[c], ps);
            pd = fmaf(acc[m][c], adv[c], pd);
        }
#pragma unroll
        for (int off = 1; off < 16; off <<= 1) {
            ps += __shfl_xor(ps, off, 64);
            pd += __shfl_xor(pd, off, 64);
        }
        if (n < N) {
            if (j == 0) { asrc[n] = ps; adst[n] = pd; }
#pragma unroll
            for (int c = 0; c < FT; c++) {
                int f = j * FT + c;
                if (f < FOUT) {
                    if constexpr (BF16OUT) {
                        ((unsigned short*)Hout)[(size_t)n * 64 + f] = f2bf(acc[m][c]);
                    } else {
                        ((float*)Hout)[(size_t)n * FOUT + f] = acc[m][c];
                    }
                }
            }
        }
    }
}

// -------------------- aggregation, FOUT in {48,60}: bf16 H rows --------------------
// One wave per dst node. Chunked two-phase: A) one edge per lane -> w,src to
// LDS + ssum partial; B) all lanes sweep LDS pairs, gather one bf16 line per
// edge, FMA. Same-wave LDS RAW needs no barrier.

#define CHUNK 128

template <int FOUT, bool RELU>
__global__ __launch_bounds__(256) void agg_bf16_kernel(
    const int* __restrict__ rowptr, const int* __restrict__ csr,
    const float* __restrict__ asrc, const float* __restrict__ adst,
    const unsigned short* __restrict__ hb, const float* __restrict__ bias,
    float* __restrict__ OUT, int N) {
    __shared__ int2 wslds[4][CHUNK];   // {src, w bits}
    const int wv = threadIdx.x >> 6;
    int n = blockIdx.x * 4 + wv;
    if (n >= N) return;
    const int lane = threadIdx.x & 63;
    const int rs = rowptr[n], re = rowptr[n + 1];
    const float ad_n = adst[n];
    const float wself = __expf(leaky(asrc[n] + ad_n));
    const int fc = (lane < FOUT) ? lane : FOUT - 1;  // clamp: dup load, never stored

    float acc = wself * bf2f(hb[(size_t)n * 64 + fc]);
    float wpart = 0.f;

    for (int base = rs; base < re; base += CHUNK) {
        const int cnt = min(CHUNK, re - base);
        // ---- phase A: one edge per lane ----
        if (lane < cnt) {
            int s = csr[base + lane];
            float w = __expf(leaky(asrc[s] + ad_n));
            wpart += w;
            wslds[wv][lane] = make_int2(s, __float_as_int(w));
        }
        // ---- phase B: sweep pairs, gather bf16 rows ----
        int i = 0;
        for (; i + 8 <= cnt; i += 8) {
            int2 p[8];
#pragma unroll
            for (int u = 0; u < 8; u++) p[u] = wslds[wv][i + u];
            float hv[8];
#pragma unroll
            for (int u = 0; u < 8; u++) hv[u] = bf2f(hb[(size_t)p[u].x * 64 + fc]);
#pragma unroll
            for (int u = 0; u < 8; u++) acc = fmaf(__int_as_float(p[u].y), hv[u], acc);
        }
        for (; i < cnt; i++) {
            int2 pp = wslds[wv][i];
            acc = fmaf(__int_as_float(pp.y), bf2f(hb[(size_t)pp.x * 64 + fc]), acc);
        }
    }

    // reduce ssum partials (phase-A lanes) across the wave
#pragma unroll
    for (int off = 32; off; off >>= 1) wpart += __shfl_xor(wpart, off, 64);
    float ssum = wpart + wself;

    if (lane < FOUT) {
        float o = acc / (ssum + 1e-16f) + bias[lane];
        if (RELU) o = fmaxf(o, 0.f);
        OUT[(size_t)n * FOUT + lane] = o;
    }
}

// -------------------- aggregation, FOUT == 1 (scalar h, fp32, L2-resident) ----------

template <bool RELU>
__global__ __launch_bounds__(256) void agg1_kernel(
    const int* __restrict__ rowptr, const int* __restrict__ csr,
    const float* __restrict__ asrc, const float* __restrict__ adst,
    const float* __restrict__ H, const float* __restrict__ bias,
    float* __restrict__ OUT, int N) {
    int n = blockIdx.x * 4 + (threadIdx.x >> 6);
    if (n >= N) return;
    int lane = threadIdx.x & 63;
    int rs = rowptr[n], re = rowptr[n + 1];
    float ad_n = adst[n];
    float wself = __expf(leaky(asrc[n] + ad_n));

    float ssum = 0.f, accv = 0.f;
    for (int e = rs + lane; e < re; e += 64) {
        int s = csr[e];
        float w = __expf(leaky(asrc[s] + ad_n));
        ssum += w;
        accv = fmaf(w, H[s], accv);
    }
#pragma unroll
    for (int off = 32; off; off >>= 1) {
        ssum += __shfl_xor(ssum, off, 64);
        accv += __shfl_xor(accv, off, 64);
    }
    ssum += wself;
    accv = fmaf(wself, H[n], accv);
    if (lane == 0) {
        float o = accv / (ssum + 1e-16f) + bias[0];
        if (RELU) o = fmaxf(o, 0.f);
        OUT[n] = o;
    }
}

// -------------------- host launcher --------------------

extern "C" void kernel_launch(void* const* d_in, const int* in_sizes, int n_in,
                              void* d_out, int out_size, void* d_ws, size_t ws_size,
                              hipStream_t stream) {
    const float* x      = (const float*)d_in[0];
    const int*   ei     = (const int*)d_in[1];   // int32 per harness convention
    // d_in[2] = edge_attr: ignored by reference (no edge_dim)
    const float* W1  = (const float*)d_in[3];
    const float* as1 = (const float*)d_in[4];
    const float* ad1 = (const float*)d_in[5];
    const float* b1  = (const float*)d_in[6];
    const float* W2  = (const float*)d_in[7];
    const float* as2 = (const float*)d_in[8];
    const float* ad2 = (const float*)d_in[9];
    const float* b2  = (const float*)d_in[10];
    const float* W3  = (const float*)d_in[11];
    const float* as3 = (const float*)d_in[12];
    const float* ad3 = (const float*)d_in[13];
    const float* b3  = (const float*)d_in[14];

    const int N = in_sizes[0] / 256;   // 50000
    const int E = in_sizes[1] / 2;     // 1600000
    const int K = (N + (1 << BSHIFT) - 1) >> BSHIFT;   // 391 buckets

    char* p = (char*)d_ws;
    auto alloc = [&](size_t bytes) -> void* {
        void* r = (void*)p;
        p += ((bytes + 255) / 256) * 256;
        return r;
    };
    int*   gcursor = (int*)alloc(512 * 4);
    int*   bbase   = (int*)alloc(512 * 4);
    int*   rowptr  = (int*)alloc(((size_t)N + 1) * 4);
    int*   csr     = (int*)alloc((size_t)E * 4);
    unsigned short* hb = (unsigned short*)alloc((size_t)N * 64 * 2);  // bf16 H, 128B rows
    float* actbuf  = (float*)alloc((size_t)N * 60 * 4);               // act1(48)/act2(60)
    float* h3      = (float*)alloc((size_t)N * 4);
    float* asrc    = (float*)alloc((size_t)N * 4);
    float* adst    = (float*)alloc((size_t)N * 4);
    // staged bucket regions (8 MB) alias actbuf (12 MB, dead until first agg):
    unsigned int* staged = (unsigned int*)actbuf;

    // ---- CSR build (two-level bucketed counting sort) ----
    hipMemsetAsync(gcursor, 0, 512 * 4, stream);
    int cblocks = (E + CTILE - 1) / CTILE;
    coarse_bin_kernel<<<cblocks, 256, 0, stream>>>(ei, staged, gcursor, E, K);
    bucket_scan_kernel<<<1, 512, 0, stream>>>(gcursor, bbase, K);
    fine_sort_kernel<<<K, 256, 0, stream>>>(staged, gcursor, bbase, rowptr, csr, N, E);

    int gblocks = (N + 63) / 64;
    int ablocks = (N + 3) / 4;

    // ---- layer 1: 256 -> 48, relu ----
    gemm_alpha_kernel<256, 48, 3, true><<<gblocks, 256, 0, stream>>>(x, W1, as1, ad1, hb, asrc, adst, N);
    agg_bf16_kernel<48, true><<<ablocks, 256, 0, stream>>>(rowptr, csr, asrc, adst, hb, b1, actbuf, N);

    // ---- layer 2: 48 -> 60, relu ----
    gemm_alpha_kernel<48, 60, 4, true><<<gblocks, 256, 0, stream>>>(actbuf, W2, as2, ad2, hb, asrc, adst, N);
    agg_bf16_kernel<60, true><<<ablocks, 256, 0, stream>>>(rowptr, csr, asrc, adst, hb, b2, actbuf, N);

    // ---- layer 3: 60 -> 1, no relu, straight to d_out ----
    gemm_alpha_kernel<60, 1, 1, false><<<gblocks, 256, 0, stream>>>(actbuf, W3, as3, ad3, h3, asrc, adst, N);
    agg1_kernel<false><<<ablocks, 256, 0, stream>>>(rowptr, csr, asrc, adst, h3, b3, (float*)d_out, N);
}

// Round 7
// 308.470 us; speedup vs baseline: 2.4118x; 1.1017x over previous
//
#include <hip/hip_runtime.h>
#include <cstdint>
#include <cstddef>

// ---------------------------------------------------------------------------
// GAT 3-layer forward, MI355X.
// Round 7: GEMM restructured from 64n x 16fg (16x redundant x loads, 56 us)
// to 64n x 4fg quads (FT=12/15): quad lanes share one x address (coalescer
// serves 4 lanes per L1 transaction), W^T LDS reads are 4-addr broadcasts.
// Layer 3 fused: gemm_out1 computes h3 only; agg1 derives alpha terms from
// h3 analytically (halves its gather arrays).
// ---------------------------------------------------------------------------

__device__ __forceinline__ float leaky(float v) { return v > 0.f ? v : 0.2f * v; }

__device__ __forceinline__ unsigned short f2bf(float x) {
    unsigned int u = __float_as_uint(x);
    u = (u + 0x7FFFu + ((u >> 16) & 1u)) >> 16;   // RNE
    return (unsigned short)u;
}
__device__ __forceinline__ float bf2f(unsigned short b) {
    return __uint_as_float(((unsigned int)b) << 16);
}

#define BSHIFT 7                 // 128 nodes per bucket
#define BCAP   5120              // slots per bucket region (mean 4096, +16 sigma)
#define CTILE  8192              // edges per coarse block

// -------------------- coarse bin: edges -> bucket regions --------------------

__global__ __launch_bounds__(256) void coarse_bin_kernel(
    const int* __restrict__ ei, unsigned int* __restrict__ staged,
    int* __restrict__ gcursor, int E, int K) {
    __shared__ int hist[512];
    __shared__ int rank[512];
    __shared__ int base[512];
    for (int b = threadIdx.x; b < K; b += 256) { hist[b] = 0; rank[b] = 0; }
    __syncthreads();

    int e0 = blockIdx.x * CTILE;
    int e1 = min(E, e0 + CTILE);

    for (int e = e0 + threadIdx.x; e < e1; e += 256) {
        int d = ei[E + e];
        atomicAdd(&hist[d >> BSHIFT], 1);
    }
    __syncthreads();

    for (int b = threadIdx.x; b < K; b += 256) {
        int c = hist[b];
        base[b] = c ? atomicAdd(&gcursor[b], c) : 0;
    }
    __syncthreads();

    for (int e = e0 + threadIdx.x; e < e1; e += 256) {
        int s = ei[e];
        int d = ei[E + e];
        int b = d >> BSHIFT;
        int r = atomicAdd(&rank[b], 1);
        staged[(size_t)b * BCAP + base[b] + r] =
            ((unsigned int)(d & ((1 << BSHIFT) - 1)) << 16) | (unsigned int)s;
    }
}

// -------------------- bucket base scan (1 block) --------------------

__global__ __launch_bounds__(512) void bucket_scan_kernel(
    const int* __restrict__ gcursor, int* __restrict__ bbase, int K) {
    __shared__ int sh[512];
    int t = threadIdx.x;
    int v = (t < K) ? gcursor[t] : 0;
    sh[t] = v;
    __syncthreads();
    for (int off = 1; off < 512; off <<= 1) {
        int a = (t >= off) ? sh[t - off] : 0;
        __syncthreads();
        sh[t] += a;
        __syncthreads();
    }
    if (t < K) bbase[t] = sh[t] - v;   // exclusive
}

// -------------------- fine pass: bucket -> rowptr + sorted csr --------------------

__global__ __launch_bounds__(256) void fine_sort_kernel(
    const unsigned int* __restrict__ staged, const int* __restrict__ gcursor,
    const int* __restrict__ bbase, int* __restrict__ rowptr, int* __restrict__ csr,
    int N, int E) {
    __shared__ int cnt[128];
    __shared__ int off[128];
    __shared__ int lcsr[BCAP];
    const int b = blockIdx.x;
    const int t = threadIdx.x;
    const int c = gcursor[b];
    const int gb = bbase[b];
    const unsigned int* rec = staged + (size_t)b * BCAP;

    if (t < 128) cnt[t] = 0;
    __syncthreads();

    for (int i = t; i < c; i += 256) atomicAdd(&cnt[rec[i] >> 16], 1);
    __syncthreads();

    if (t < 128) off[t] = cnt[t];
    __syncthreads();
    for (int s = 1; s < 128; s <<= 1) {
        int a = (t >= s && t < 128) ? off[t - s] : 0;
        __syncthreads();
        if (t < 128) off[t] += a;
        __syncthreads();
    }

    if (t < 128) {
        int excl = off[t] - cnt[t];
        int n = (b << BSHIFT) + t;
        if (n <= N) rowptr[n] = gb + excl;
        cnt[t] = excl;
    }
    if (b == 0 && t == 0) rowptr[N] = E;
    __syncthreads();

    for (int i = t; i < c; i += 256) {
        unsigned int r = rec[i];
        int p = atomicAdd(&cnt[r >> 16], 1);
        lcsr[p] = (int)(r & 0xFFFFu);
    }
    __syncthreads();

    for (int i = t; i < c; i += 256) csr[gb + i] = lcsr[i];
}

// -------------------- fused GEMM + alpha (layers 1-2, bf16 H out) --------------------
// 256 threads = 64 nodes x 4 fout-groups (quads). i = tid>>2 node, j = tid&3.
// Quad lanes load the same x float4 (coalescer: one L1 transaction serves 4).
// W^T LDS reads: 4 distinct broadcast addresses per wave. FT = FOUT/4.

template <int FIN, int FOUT, int FT>
__global__ __launch_bounds__(256) void gemm_alpha_kernel(
    const float* __restrict__ X, const float* __restrict__ W,
    const float* __restrict__ avs, const float* __restrict__ avd,
    unsigned short* __restrict__ hb, float* __restrict__ asrc, float* __restrict__ adst,
    int N) {
    static_assert(4 * FT == FOUT, "FT must be FOUT/4");
    constexpr int PITCH = FIN + 4;
    __shared__ float Wt[FOUT][PITCH];
    for (int idx = threadIdx.x; idx < FOUT * FIN; idx += 256) {
        int k = idx % FIN, f = idx / FIN;
        Wt[f][k] = W[k * FOUT + f];
    }
    __syncthreads();

    const int j = threadIdx.x & 3;    // fout group (quad lane)
    const int i = threadIdx.x >> 2;   // node (0..63)
    const int n = blockIdx.x * 64 + i;
    const int nc = (n < N) ? n : N - 1;  // clamp loads; stores guarded

    float acc[FT];
#pragma unroll
    for (int c = 0; c < FT; c++) acc[c] = 0.f;

    const float* xrow = X + (size_t)nc * FIN;

    for (int k = 0; k < FIN; k += 4) {
        float4 xv = *(const float4*)(xrow + k);
#pragma unroll
        for (int c = 0; c < FT; c++) {
            float4 wv = *(const float4*)&Wt[j * FT + c][k];
            acc[c] = fmaf(xv.x, wv.x,
                      fmaf(xv.y, wv.y,
                       fmaf(xv.z, wv.z,
                        fmaf(xv.w, wv.w, acc[c]))));
        }
    }

    // alpha partials for this quad-lane, then quad reduce (lanes 4i..4i+3)
    float ps = 0.f, pd = 0.f;
#pragma unroll
    for (int c = 0; c < FT; c++) {
        int f = j * FT + c;
        ps = fmaf(acc[c], avs[f], ps);
        pd = fmaf(acc[c], avd[f], pd);
    }
    ps += __shfl_xor(ps, 1, 64); ps += __shfl_xor(ps, 2, 64);
    pd += __shfl_xor(pd, 1, 64); pd += __shfl_xor(pd, 2, 64);

    if (n < N) {
        if (j == 0) { asrc[n] = ps; adst[n] = pd; }
#pragma unroll
        for (int c = 0; c < FT; c++)
            hb[(size_t)n * 64 + j * FT + c] = f2bf(acc[c]);
    }
}

// -------------------- aggregation, FOUT in {48,60}: bf16 H rows --------------------

#define CHUNK 128

template <int FOUT, bool RELU>
__global__ __launch_bounds__(256) void agg_bf16_kernel(
    const int* __restrict__ rowptr, const int* __restrict__ csr,
    const float* __restrict__ asrc, const float* __restrict__ adst,
    const unsigned short* __restrict__ hb, const float* __restrict__ bias,
    float* __restrict__ OUT, int N) {
    __shared__ int2 wslds[4][CHUNK];   // {src, w bits}
    const int wv = threadIdx.x >> 6;
    int n = blockIdx.x * 4 + wv;
    if (n >= N) return;
    const int lane = threadIdx.x & 63;
    const int rs = rowptr[n], re = rowptr[n + 1];
    const float ad_n = adst[n];
    const float wself = __expf(leaky(asrc[n] + ad_n));
    const int fc = (lane < FOUT) ? lane : FOUT - 1;  // clamp: dup load, never stored

    float acc = wself * bf2f(hb[(size_t)n * 64 + fc]);
    float wpart = 0.f;

    for (int base = rs; base < re; base += CHUNK) {
        const int cnt = min(CHUNK, re - base);
        if (lane < cnt) {
            int s = csr[base + lane];
            float w = __expf(leaky(asrc[s] + ad_n));
            wpart += w;
            wslds[wv][lane] = make_int2(s, __float_as_int(w));
        }
        int i = 0;
        for (; i + 8 <= cnt; i += 8) {
            int2 p[8];
#pragma unroll
            for (int u = 0; u < 8; u++) p[u] = wslds[wv][i + u];
            float hv[8];
#pragma unroll
            for (int u = 0; u < 8; u++) hv[u] = bf2f(hb[(size_t)p[u].x * 64 + fc]);
#pragma unroll
            for (int u = 0; u < 8; u++) acc = fmaf(__int_as_float(p[u].y), hv[u], acc);
        }
        for (; i < cnt; i++) {
            int2 pp = wslds[wv][i];
            acc = fmaf(__int_as_float(pp.y), bf2f(hb[(size_t)pp.x * 64 + fc]), acc);
        }
    }

#pragma unroll
    for (int off = 32; off; off >>= 1) wpart += __shfl_xor(wpart, off, 64);
    float ssum = wpart + wself;

    if (lane < FOUT) {
        float o = acc / (ssum + 1e-16f) + bias[lane];
        if (RELU) o = fmaxf(o, 0.f);
        OUT[(size_t)n * FOUT + lane] = o;
    }
}

// -------------------- layer 3: h3 = act2 . W3 (60 -> 1) --------------------

__global__ __launch_bounds__(256) void gemm_out1_kernel(
    const float* __restrict__ act, const float* __restrict__ W3,
    float* __restrict__ h3, int N) {
    __shared__ float w[60];
    if (threadIdx.x < 60) w[threadIdx.x] = W3[threadIdx.x];
    __syncthreads();
    int n = blockIdx.x * 256 + threadIdx.x;
    if (n >= N) return;
    const float4* row = (const float4*)(act + (size_t)n * 60);
    float s = 0.f;
#pragma unroll
    for (int q = 0; q < 15; q++) {
        float4 v = row[q];
        s = fmaf(v.x, w[4 * q + 0],
             fmaf(v.y, w[4 * q + 1],
              fmaf(v.z, w[4 * q + 2],
               fmaf(v.w, w[4 * q + 3], s))));
    }
    h3[n] = s;
}

// -------------------- layer-3 aggregation: alpha derived from h3 --------------------
// asrc[s] = as3*h3[s], adst[n] = ad3*h3[n] -> single gather array (h3).

__global__ __launch_bounds__(256) void agg1_kernel(
    const int* __restrict__ rowptr, const int* __restrict__ csr,
    const float* __restrict__ h3,
    const float* __restrict__ as3p, const float* __restrict__ ad3p,
    const float* __restrict__ bias, float* __restrict__ OUT, int N) {
    int n = blockIdx.x * 4 + (threadIdx.x >> 6);
    if (n >= N) return;
    int lane = threadIdx.x & 63;
    int rs = rowptr[n], re = rowptr[n + 1];
    const float a_s = as3p[0];
    float hn = h3[n];
    float adn = ad3p[0] * hn;
    float wself = __expf(leaky(a_s * hn + adn));

    float ssum = 0.f, accv = 0.f;
    for (int e = rs + lane; e < re; e += 64) {
        float hs = h3[csr[e]];
        float w = __expf(leaky(a_s * hs + adn));
        ssum += w;
        accv = fmaf(w, hs, accv);
    }
#pragma unroll
    for (int off = 32; off; off >>= 1) {
        ssum += __shfl_xor(ssum, off, 64);
        accv += __shfl_xor(accv, off, 64);
    }
    ssum += wself;
    accv = fmaf(wself, hn, accv);
    if (lane == 0) OUT[n] = accv / (ssum + 1e-16f) + bias[0];
}

// -------------------- host launcher --------------------

extern "C" void kernel_launch(void* const* d_in, const int* in_sizes, int n_in,
                              void* d_out, int out_size, void* d_ws, size_t ws_size,
                              hipStream_t stream) {
    const float* x      = (const float*)d_in[0];
    const int*   ei     = (const int*)d_in[1];   // int32 per harness convention
    // d_in[2] = edge_attr: ignored by reference (no edge_dim)
    const float* W1  = (const float*)d_in[3];
    const float* as1 = (const float*)d_in[4];
    const float* ad1 = (const float*)d_in[5];
    const float* b1  = (const float*)d_in[6];
    const float* W2  = (const float*)d_in[7];
    const float* as2 = (const float*)d_in[8];
    const float* ad2 = (const float*)d_in[9];
    const float* b2  = (const float*)d_in[10];
    const float* W3  = (const float*)d_in[11];
    // as3/ad3 consumed inside agg1 (scalar): d_in[12], d_in[13]
    const float* as3 = (const float*)d_in[12];
    const float* ad3 = (const float*)d_in[13];
    const float* b3  = (const float*)d_in[14];

    const int N = in_sizes[0] / 256;   // 50000
    const int E = in_sizes[1] / 2;     // 1600000
    const int K = (N + (1 << BSHIFT) - 1) >> BSHIFT;   // 391 buckets

    char* p = (char*)d_ws;
    auto alloc = [&](size_t bytes) -> void* {
        void* r = (void*)p;
        p += ((bytes + 255) / 256) * 256;
        return r;
    };
    int*   gcursor = (int*)alloc(512 * 4);
    int*   bbase   = (int*)alloc(512 * 4);
    int*   rowptr  = (int*)alloc(((size_t)N + 1) * 4);
    int*   csr     = (int*)alloc((size_t)E * 4);
    unsigned short* hb = (unsigned short*)alloc((size_t)N * 64 * 2);  // bf16 H, 128B rows
    float* actbuf  = (float*)alloc((size_t)N * 60 * 4);               // act1(48)/act2(60)
    float* h3      = (float*)alloc((size_t)N * 4);
    float* asrc    = (float*)alloc((size_t)N * 4);
    float* adst    = (float*)alloc((size_t)N * 4);
    // staged bucket regions (8 MB) alias actbuf (12 MB, dead until first agg):
    unsigned int* staged = (unsigned int*)actbuf;

    // ---- CSR build (two-level bucketed counting sort) ----
    hipMemsetAsync(gcursor, 0, 512 * 4, stream);
    int cblocks = (E + CTILE - 1) / CTILE;
    coarse_bin_kernel<<<cblocks, 256, 0, stream>>>(ei, staged, gcursor, E, K);
    bucket_scan_kernel<<<1, 512, 0, stream>>>(gcursor, bbase, K);
    fine_sort_kernel<<<K, 256, 0, stream>>>(staged, gcursor, bbase, rowptr, csr, N, E);

    int gblocks = (N + 63) / 64;
    int ablocks = (N + 3) / 4;

    // ---- layer 1: 256 -> 48, relu ----
    gemm_alpha_kernel<256, 48, 12><<<gblocks, 256, 0, stream>>>(x, W1, as1, ad1, hb, asrc, adst, N);
    agg_bf16_kernel<48, true><<<ablocks, 256, 0, stream>>>(rowptr, csr, asrc, adst, hb, b1, actbuf, N);

    // ---- layer 2: 48 -> 60, relu ----
    gemm_alpha_kernel<48, 60, 15><<<gblocks, 256, 0, stream>>>(actbuf, W2, as2, ad2, hb, asrc, adst, N);
    agg_bf16_kernel<60, true><<<ablocks, 256, 0, stream>>>(rowptr, csr, asrc, adst, hb, b2, actbuf, N);

    // ---- layer 3: 60 -> 1, no relu, straight to d_out ----
    gemm_out1_kernel<<<(N + 255) / 256, 256, 0, stream>>>(actbuf, W3, h3, N);
    agg1_kernel<<<ablocks, 256, 0, stream>>>(rowptr, csr, h3, as3, ad3, b3, (float*)d_out, N);
}

// Round 8
// 298.418 us; speedup vs baseline: 2.4931x; 1.0337x over previous
//
#include <hip/hip_runtime.h>
#include <cstdint>
#include <cstddef>

// ---------------------------------------------------------------------------
// GAT 3-layer forward, MI355X.
// Round 8: GEMM now 128 nodes/block, thread = quad-lane j (fout group) x
// M=2 nodes. Quad shares x float4 loads (round-7 win) AND each LDS W-read
// feeds M*4 FMAs (fixes round-7's LDS-throughput bound: LDS 9216 cyc vs
// FMA 12288 cyc per wave -> FMA-bound). Round-7 profile: gemm1 59 us,
// VALUBusy 34%, LDS-read:FMA issue 1.5:1.
// ---------------------------------------------------------------------------

__device__ __forceinline__ float leaky(float v) { return v > 0.f ? v : 0.2f * v; }

__device__ __forceinline__ unsigned short f2bf(float x) {
    unsigned int u = __float_as_uint(x);
    u = (u + 0x7FFFu + ((u >> 16) & 1u)) >> 16;   // RNE
    return (unsigned short)u;
}
__device__ __forceinline__ float bf2f(unsigned short b) {
    return __uint_as_float(((unsigned int)b) << 16);
}

#define BSHIFT 7                 // 128 nodes per bucket
#define BCAP   5120              // slots per bucket region (mean 4096, +16 sigma)
#define CTILE  8192              // edges per coarse block

// -------------------- coarse bin: edges -> bucket regions --------------------

__global__ __launch_bounds__(256) void coarse_bin_kernel(
    const int* __restrict__ ei, unsigned int* __restrict__ staged,
    int* __restrict__ gcursor, int E, int K) {
    __shared__ int hist[512];
    __shared__ int rank[512];
    __shared__ int base[512];
    for (int b = threadIdx.x; b < K; b += 256) { hist[b] = 0; rank[b] = 0; }
    __syncthreads();

    int e0 = blockIdx.x * CTILE;
    int e1 = min(E, e0 + CTILE);

    for (int e = e0 + threadIdx.x; e < e1; e += 256) {
        int d = ei[E + e];
        atomicAdd(&hist[d >> BSHIFT], 1);
    }
    __syncthreads();

    for (int b = threadIdx.x; b < K; b += 256) {
        int c = hist[b];
        base[b] = c ? atomicAdd(&gcursor[b], c) : 0;
    }
    __syncthreads();

    for (int e = e0 + threadIdx.x; e < e1; e += 256) {
        int s = ei[e];
        int d = ei[E + e];
        int b = d >> BSHIFT;
        int r = atomicAdd(&rank[b], 1);
        staged[(size_t)b * BCAP + base[b] + r] =
            ((unsigned int)(d & ((1 << BSHIFT) - 1)) << 16) | (unsigned int)s;
    }
}

// -------------------- bucket base scan (1 block) --------------------

__global__ __launch_bounds__(512) void bucket_scan_kernel(
    const int* __restrict__ gcursor, int* __restrict__ bbase, int K) {
    __shared__ int sh[512];
    int t = threadIdx.x;
    int v = (t < K) ? gcursor[t] : 0;
    sh[t] = v;
    __syncthreads();
    for (int off = 1; off < 512; off <<= 1) {
        int a = (t >= off) ? sh[t - off] : 0;
        __syncthreads();
        sh[t] += a;
        __syncthreads();
    }
    if (t < K) bbase[t] = sh[t] - v;   // exclusive
}

// -------------------- fine pass: bucket -> rowptr + sorted csr --------------------

__global__ __launch_bounds__(256) void fine_sort_kernel(
    const unsigned int* __restrict__ staged, const int* __restrict__ gcursor,
    const int* __restrict__ bbase, int* __restrict__ rowptr, int* __restrict__ csr,
    int N, int E) {
    __shared__ int cnt[128];
    __shared__ int off[128];
    __shared__ int lcsr[BCAP];
    const int b = blockIdx.x;
    const int t = threadIdx.x;
    const int c = gcursor[b];
    const int gb = bbase[b];
    const unsigned int* rec = staged + (size_t)b * BCAP;

    if (t < 128) cnt[t] = 0;
    __syncthreads();

    for (int i = t; i < c; i += 256) atomicAdd(&cnt[rec[i] >> 16], 1);
    __syncthreads();

    if (t < 128) off[t] = cnt[t];
    __syncthreads();
    for (int s = 1; s < 128; s <<= 1) {
        int a = (t >= s && t < 128) ? off[t - s] : 0;
        __syncthreads();
        if (t < 128) off[t] += a;
        __syncthreads();
    }

    if (t < 128) {
        int excl = off[t] - cnt[t];
        int n = (b << BSHIFT) + t;
        if (n <= N) rowptr[n] = gb + excl;
        cnt[t] = excl;
    }
    if (b == 0 && t == 0) rowptr[N] = E;
    __syncthreads();

    for (int i = t; i < c; i += 256) {
        unsigned int r = rec[i];
        int p = atomicAdd(&cnt[r >> 16], 1);
        lcsr[p] = (int)(r & 0xFFFFu);
    }
    __syncthreads();

    for (int i = t; i < c; i += 256) csr[gb + i] = lcsr[i];
}

// -------------------- fused GEMM + alpha (layers 1-2, bf16 H out) --------------------
// 256 threads = 64 quad-slots x 4 fout-groups; each thread owns M=2 nodes.
// Quad lanes share x float4 addresses (one L1 transaction serves 4 lanes);
// each Wt ds_read_b128 feeds M*4 FMAs -> FMA-bound.

template <int FIN, int FOUT, int FT, int M>
__global__ __launch_bounds__(256) void gemm_alpha_kernel(
    const float* __restrict__ X, const float* __restrict__ W,
    const float* __restrict__ avs, const float* __restrict__ avd,
    unsigned short* __restrict__ hb, float* __restrict__ asrc, float* __restrict__ adst,
    int N) {
    static_assert(4 * FT == FOUT, "FT must be FOUT/4");
    constexpr int PITCH = FIN + 4;
    __shared__ float Wt[FOUT][PITCH];
    for (int idx = threadIdx.x; idx < FOUT * FIN; idx += 256) {
        int k = idx % FIN, f = idx / FIN;
        Wt[f][k] = W[k * FOUT + f];
    }
    __syncthreads();

    const int j = threadIdx.x & 3;    // fout group (quad lane)
    const int i = threadIdx.x >> 2;   // node slot (0..63)
    const int nbase = blockIdx.x * 64 * M + i * M;

    float acc[M][FT];
#pragma unroll
    for (int m = 0; m < M; m++)
#pragma unroll
        for (int c = 0; c < FT; c++) acc[m][c] = 0.f;

    const float* xrow[M];
#pragma unroll
    for (int m = 0; m < M; m++) {
        int n = nbase + m;
        if (n > N - 1) n = N - 1;    // clamp loads; stores guarded below
        xrow[m] = X + (size_t)n * FIN;
    }

    for (int k = 0; k < FIN; k += 4) {
        float4 xv[M];
#pragma unroll
        for (int m = 0; m < M; m++) xv[m] = *(const float4*)(xrow[m] + k);
#pragma unroll
        for (int c = 0; c < FT; c++) {
            float4 wv = *(const float4*)&Wt[j * FT + c][k];
#pragma unroll
            for (int m = 0; m < M; m++) {
                acc[m][c] = fmaf(xv[m].x, wv.x,
                             fmaf(xv[m].y, wv.y,
                              fmaf(xv[m].z, wv.z,
                               fmaf(xv[m].w, wv.w, acc[m][c]))));
            }
        }
    }

    float asv[FT], adv[FT];
#pragma unroll
    for (int c = 0; c < FT; c++) {
        asv[c] = avs[j * FT + c];
        adv[c] = avd[j * FT + c];
    }

#pragma unroll
    for (int m = 0; m < M; m++) {
        int n = nbase + m;
        float ps = 0.f, pd = 0.f;
#pragma unroll
        for (int c = 0; c < FT; c++) {
            ps = fmaf(acc[m][c], asv[c], ps);
            pd = fmaf(acc[m][c], adv[c], pd);
        }
        ps += __shfl_xor(ps, 1, 64); ps += __shfl_xor(ps, 2, 64);
        pd += __shfl_xor(pd, 1, 64); pd += __shfl_xor(pd, 2, 64);
        if (n < N) {
            if (j == 0) { asrc[n] = ps; adst[n] = pd; }
#pragma unroll
            for (int c = 0; c < FT; c++)
                hb[(size_t)n * 64 + j * FT + c] = f2bf(acc[m][c]);
        }
    }
}

// -------------------- aggregation, FOUT in {48,60}: bf16 H rows --------------------

#define CHUNK 128

template <int FOUT, bool RELU>
__global__ __launch_bounds__(256) void agg_bf16_kernel(
    const int* __restrict__ rowptr, const int* __restrict__ csr,
    const float* __restrict__ asrc, const float* __restrict__ adst,
    const unsigned short* __restrict__ hb, const float* __restrict__ bias,
    float* __restrict__ OUT, int N) {
    __shared__ int2 wslds[4][CHUNK];   // {src, w bits}
    const int wv = threadIdx.x >> 6;
    int n = blockIdx.x * 4 + wv;
    if (n >= N) return;
    const int lane = threadIdx.x & 63;
    const int rs = rowptr[n], re = rowptr[n + 1];
    const float ad_n = adst[n];
    const float wself = __expf(leaky(asrc[n] + ad_n));
    const int fc = (lane < FOUT) ? lane : FOUT - 1;  // clamp: dup load, never stored

    float acc = wself * bf2f(hb[(size_t)n * 64 + fc]);
    float wpart = 0.f;

    for (int base = rs; base < re; base += CHUNK) {
        const int cnt = min(CHUNK, re - base);
        if (lane < cnt) {
            int s = csr[base + lane];
            float w = __expf(leaky(asrc[s] + ad_n));
            wpart += w;
            wslds[wv][lane] = make_int2(s, __float_as_int(w));
        }
        int i = 0;
        for (; i + 8 <= cnt; i += 8) {
            int2 p[8];
#pragma unroll
            for (int u = 0; u < 8; u++) p[u] = wslds[wv][i + u];
            float hv[8];
#pragma unroll
            for (int u = 0; u < 8; u++) hv[u] = bf2f(hb[(size_t)p[u].x * 64 + fc]);
#pragma unroll
            for (int u = 0; u < 8; u++) acc = fmaf(__int_as_float(p[u].y), hv[u], acc);
        }
        for (; i < cnt; i++) {
            int2 pp = wslds[wv][i];
            acc = fmaf(__int_as_float(pp.y), bf2f(hb[(size_t)pp.x * 64 + fc]), acc);
        }
    }

#pragma unroll
    for (int off = 32; off; off >>= 1) wpart += __shfl_xor(wpart, off, 64);
    float ssum = wpart + wself;

    if (lane < FOUT) {
        float o = acc / (ssum + 1e-16f) + bias[lane];
        if (RELU) o = fmaxf(o, 0.f);
        OUT[(size_t)n * FOUT + lane] = o;
    }
}

// -------------------- layer 3: h3 = act2 . W3 (60 -> 1) --------------------

__global__ __launch_bounds__(256) void gemm_out1_kernel(
    const float* __restrict__ act, const float* __restrict__ W3,
    float* __restrict__ h3, int N) {
    __shared__ float w[60];
    if (threadIdx.x < 60) w[threadIdx.x] = W3[threadIdx.x];
    __syncthreads();
    int n = blockIdx.x * 256 + threadIdx.x;
    if (n >= N) return;
    const float4* row = (const float4*)(act + (size_t)n * 60);
    float s = 0.f;
#pragma unroll
    for (int q = 0; q < 15; q++) {
        float4 v = row[q];
        s = fmaf(v.x, w[4 * q + 0],
             fmaf(v.y, w[4 * q + 1],
              fmaf(v.z, w[4 * q + 2],
               fmaf(v.w, w[4 * q + 3], s))));
    }
    h3[n] = s;
}

// -------------------- layer-3 aggregation: alpha derived from h3 --------------------

__global__ __launch_bounds__(256) void agg1_kernel(
    const int* __restrict__ rowptr, const int* __restrict__ csr,
    const float* __restrict__ h3,
    const float* __restrict__ as3p, const float* __restrict__ ad3p,
    const float* __restrict__ bias, float* __restrict__ OUT, int N) {
    int n = blockIdx.x * 4 + (threadIdx.x >> 6);
    if (n >= N) return;
    int lane = threadIdx.x & 63;
    int rs = rowptr[n], re = rowptr[n + 1];
    const float a_s = as3p[0];
    float hn = h3[n];
    float adn = ad3p[0] * hn;
    float wself = __expf(leaky(a_s * hn + adn));

    float ssum = 0.f, accv = 0.f;
    for (int e = rs + lane; e < re; e += 64) {
        float hs = h3[csr[e]];
        float w = __expf(leaky(a_s * hs + adn));
        ssum += w;
        accv = fmaf(w, hs, accv);
    }
#pragma unroll
    for (int off = 32; off; off >>= 1) {
        ssum += __shfl_xor(ssum, off, 64);
        accv += __shfl_xor(accv, off, 64);
    }
    ssum += wself;
    accv = fmaf(wself, hn, accv);
    if (lane == 0) OUT[n] = accv / (ssum + 1e-16f) + bias[0];
}

// -------------------- host launcher --------------------

extern "C" void kernel_launch(void* const* d_in, const int* in_sizes, int n_in,
                              void* d_out, int out_size, void* d_ws, size_t ws_size,
                              hipStream_t stream) {
    const float* x      = (const float*)d_in[0];
    const int*   ei     = (const int*)d_in[1];   // int32 per harness convention
    // d_in[2] = edge_attr: ignored by reference (no edge_dim)
    const float* W1  = (const float*)d_in[3];
    const float* as1 = (const float*)d_in[4];
    const float* ad1 = (const float*)d_in[5];
    const float* b1  = (const float*)d_in[6];
    const float* W2  = (const float*)d_in[7];
    const float* as2 = (const float*)d_in[8];
    const float* ad2 = (const float*)d_in[9];
    const float* b2  = (const float*)d_in[10];
    const float* W3  = (const float*)d_in[11];
    const float* as3 = (const float*)d_in[12];
    const float* ad3 = (const float*)d_in[13];
    const float* b3  = (const float*)d_in[14];

    const int N = in_sizes[0] / 256;   // 50000
    const int E = in_sizes[1] / 2;     // 1600000
    const int K = (N + (1 << BSHIFT) - 1) >> BSHIFT;   // 391 buckets

    char* p = (char*)d_ws;
    auto alloc = [&](size_t bytes) -> void* {
        void* r = (void*)p;
        p += ((bytes + 255) / 256) * 256;
        return r;
    };
    int*   gcursor = (int*)alloc(512 * 4);
    int*   bbase   = (int*)alloc(512 * 4);
    int*   rowptr  = (int*)alloc(((size_t)N + 1) * 4);
    int*   csr     = (int*)alloc((size_t)E * 4);
    unsigned short* hb = (unsigned short*)alloc((size_t)N * 64 * 2);  // bf16 H, 128B rows
    float* actbuf  = (float*)alloc((size_t)N * 60 * 4);               // act1(48)/act2(60)
    float* h3      = (float*)alloc((size_t)N * 4);
    float* asrc    = (float*)alloc((size_t)N * 4);
    float* adst    = (float*)alloc((size_t)N * 4);
    // staged bucket regions (8 MB) alias actbuf (12 MB, dead until first agg):
    unsigned int* staged = (unsigned int*)actbuf;

    // ---- CSR build (two-level bucketed counting sort) ----
    hipMemsetAsync(gcursor, 0, 512 * 4, stream);
    int cblocks = (E + CTILE - 1) / CTILE;
    coarse_bin_kernel<<<cblocks, 256, 0, stream>>>(ei, staged, gcursor, E, K);
    bucket_scan_kernel<<<1, 512, 0, stream>>>(gcursor, bbase, K);
    fine_sort_kernel<<<K, 256, 0, stream>>>(staged, gcursor, bbase, rowptr, csr, N, E);

    int gblocks = (N + 127) / 128;     // 128 nodes per block (M=2)
    int ablocks = (N + 3) / 4;

    // ---- layer 1: 256 -> 48, relu ----
    gemm_alpha_kernel<256, 48, 12, 2><<<gblocks, 256, 0, stream>>>(x, W1, as1, ad1, hb, asrc, adst, N);
    agg_bf16_kernel<48, true><<<ablocks, 256, 0, stream>>>(rowptr, csr, asrc, adst, hb, b1, actbuf, N);

    // ---- layer 2: 48 -> 60, relu ----
    gemm_alpha_kernel<48, 60, 15, 2><<<gblocks, 256, 0, stream>>>(actbuf, W2, as2, ad2, hb, asrc, adst, N);
    agg_bf16_kernel<60, true><<<ablocks, 256, 0, stream>>>(rowptr, csr, asrc, adst, hb, b2, actbuf, N);

    // ---- layer 3: 60 -> 1, no relu, straight to d_out ----
    gemm_out1_kernel<<<(N + 255) / 256, 256, 0, stream>>>(actbuf, W3, h3, N);
    agg1_kernel<<<ablocks, 256, 0, stream>>>(rowptr, csr, h3, as3, ad3, b3, (float*)d_out, N);
}